// Round 12
// baseline (322.177 us; speedup 1.0000x reference)
//
#include <hip/hip_runtime.h>
#include <hip/hip_bf16.h>
#include <math.h>

// Problem constants: N=50000, E=640000, M=400000
// D_IN=256, H1=128, H2=128, H3=64, D_OUT=32
//
// Round 12: fuse gather->GEMM pairs via per-wave fp16 LDS tiles:
//   fused_gather_gemm  : gather(A16) + elu + W2 MFMA -> C16   (B never exists)
//   fused_gather_heads : gather(C16) + head1 + head2 -> Z16   (embed never exists)
// t1 tile overlays the gather tile in heads (17.4 KB LDS each, launch_bounds(256,6)).
// B-frags loaded per-column in the MFMA loop to keep VGPR low (gather TLP).
// fp16->bf16 hi/lo split is exact, so only one fp16 rounding is added per fusion.

typedef __attribute__((ext_vector_type(8))) short short8v;     // 8 bf16 (4 VGPR)
typedef __attribute__((ext_vector_type(4))) float f32x4;       // MFMA acc
typedef __attribute__((ext_vector_type(4))) _Float16 half4v;   // 8B fp16 vector
typedef __attribute__((ext_vector_type(8))) _Float16 half8v;   // 16B fp16 vector

__device__ inline unsigned short f2bf_rne(float f) {
    unsigned u = __float_as_uint(f);
    unsigned r = u + 0x7FFFu + ((u >> 16) & 1u);
    return (unsigned short)(r >> 16);
}
__device__ inline float bf2f(unsigned short h) {
    return __uint_as_float(((unsigned)h) << 16);
}

// ---------------------------------------------------------------------------
// CSR build + norm (unchanged)
// ---------------------------------------------------------------------------
__global__ void zero_ideg_kernel(int* __restrict__ ideg, int n) {
    int i = blockIdx.x * 256 + threadIdx.x;
    if (i < n) ideg[i] = 0;
}

__global__ void ideg_accum_kernel(int* __restrict__ ideg, const int* __restrict__ dst, int e) {
    int i = blockIdx.x * 256 + threadIdx.x;
    if (i < e) atomicAdd(&ideg[dst[i]], 1);
}

__global__ __launch_bounds__(256) void scan_blk_kernel(const int* __restrict__ ideg,
                                                       int* __restrict__ row_ptr,
                                                       float* __restrict__ dis,
                                                       int* __restrict__ partials, int n) {
    __shared__ int wsum[4];
    const int t = threadIdx.x;
    const int lane = t & 63;
    const int wid = t >> 6;
    const int i0 = blockIdx.x * 1024 + t * 4;
    int4 v = make_int4(0, 0, 0, 0);
    if (i0 + 3 < n) {
        v = *(const int4*)&ideg[i0];
    } else if (i0 < n) {
        v.x = ideg[i0];
        if (i0 + 1 < n) v.y = ideg[i0 + 1];
        if (i0 + 2 < n) v.z = ideg[i0 + 2];
    }
    if (i0 < n) {
        dis[i0] = rsqrtf(1.f + (float)v.x);
        if (i0 + 1 < n) dis[i0 + 1] = rsqrtf(1.f + (float)v.y);
        if (i0 + 2 < n) dis[i0 + 2] = rsqrtf(1.f + (float)v.z);
        if (i0 + 3 < n) dis[i0 + 3] = rsqrtf(1.f + (float)v.w);
    }
    int s = v.x + v.y + v.z + v.w;
    int incl = s;
#pragma unroll
    for (int off = 1; off < 64; off <<= 1) {
        int tv = __shfl_up(incl, off, 64);
        if (lane >= off) incl += tv;
    }
    if (lane == 63) wsum[wid] = incl;
    __syncthreads();
    if (t == 0) {
        int a = 0;
#pragma unroll
        for (int ww = 0; ww < 4; ++ww) { int tmp = wsum[ww]; wsum[ww] = a; a += tmp; }
    }
    __syncthreads();
    int ex = wsum[wid] + incl - s;
    if (i0 < n) {
        row_ptr[i0] = ex;
        if (i0 + 1 < n) row_ptr[i0 + 1] = ex + v.x;
        if (i0 + 2 < n) row_ptr[i0 + 2] = ex + v.x + v.y;
        if (i0 + 3 < n) row_ptr[i0 + 3] = ex + v.x + v.y + v.z;
    }
    if (t == 255) partials[blockIdx.x] = wsum[3] + incl;
}

__global__ void scan_part_kernel(int* __restrict__ partials, int nb) {
    int lane = threadIdx.x;
    int v = (lane < nb) ? partials[lane] : 0;
    int incl = v;
#pragma unroll
    for (int off = 1; off < 64; off <<= 1) {
        int tv = __shfl_up(incl, off, 64);
        if (lane >= off) incl += tv;
    }
    if (lane < nb) partials[lane] = incl - v;
}

__global__ void scan_add_kernel(int* __restrict__ row_ptr, const int* __restrict__ partials, int n) {
    int i = blockIdx.x * 256 + threadIdx.x;
    if (i < n) row_ptr[i] += partials[i >> 10];
}

__global__ void fill_kernel(const int* __restrict__ src, const int* __restrict__ dst,
                            int* __restrict__ row_ptr, int* __restrict__ csr, int e) {
    int i = blockIdx.x * 256 + threadIdx.x;
    if (i < e) {
        int d = dst[i];
        int pos = atomicAdd(&row_ptr[d], 1);
        csr[pos] = src[i];
    }
}

// ---------------------------------------------------------------------------
// Weight prep in MFMA-fragment order (unchanged).
// ---------------------------------------------------------------------------
__global__ void prep_weights_kernel(
    const float* __restrict__ W1, const float* __restrict__ W2,
    const float* __restrict__ tfw1, const float* __restrict__ tfb1,
    const float* __restrict__ tfw2, const float* __restrict__ tfb2,
    const float* __restrict__ tgw1, const float* __restrict__ tgb1,
    const float* __restrict__ tgw2, const float* __restrict__ tgb2,
    unsigned short* __restrict__ wf,
    float* __restrict__ bcat1, float* __restrict__ bcat2)
{
    int id = blockIdx.x * 256 + threadIdx.x;
    if (id >= 147456) {
        if (id < 147456 + 128) {
            int c = id - 147456;
            bcat1[c] = (c < 64) ? tfb1[c] : tgb1[c - 64];
        } else if (id < 147456 + 192) {
            int c = id - 147456 - 128;
            bcat2[c] = (c < 32) ? tfb2[c] : tgb2[c - 32];
        }
        return;
    }
    int base, NF;
    int lid;
    if (id < 65536)       { base = 0;      NF = 8; lid = id; }
    else if (id < 98304)  { base = 65536;  NF = 8; lid = id - 65536; }
    else if (id < 131072) { base = 98304;  NF = 8; lid = id - 98304; }
    else                  { base = 131072; NF = 4; lid = id - 131072; }

    int j    = lid & 7;
    int lane = (lid >> 3) & 63;
    int h    = (lid >> 9) & 1;
    int rest = lid >> 10;
    int c    = rest % NF;
    int kk   = rest / NF;
    int k    = kk * 32 + (lane >> 4) * 8 + j;
    int col  = c * 16 + (lane & 15);

    float w;
    if (id < 65536) {                 // W1: [256][128]
        w = W1[k * 128 + col];
    } else if (id < 98304) {          // W2: [128][128]
        w = W2[k * 128 + col];
    } else if (id < 131072) {         // H1 cat: [128][128] = [tf_w1 | tg_w1]
        w = (col < 64) ? tfw1[k * 64 + col] : tgw1[k * 64 + (col - 64)];
    } else {                          // H2 block-diag: [128][64]
        w = 0.f;
        if (k < 64 && col < 32) w = tfw2[k * 32 + col];
        else if (k >= 64 && col >= 32) w = tgw2[(k - 64) * 32 + (col - 32)];
    }
    unsigned short hb = f2bf_rne(w);
    wf[base + lid] = h ? f2bf_rne(w - bf2f(hb)) : hb;
}

// ---------------------------------------------------------------------------
// LDS-free MFMA GEMM (layer 1 only): A16 = x @ W1, fp16 out.
// ---------------------------------------------------------------------------
template <int K, int NCOL>
__global__ __launch_bounds__(256) void mfma_gemm_kernel(
    const float* __restrict__ X, const unsigned short* __restrict__ wf,
    _Float16* __restrict__ Y, int nrows)
{
    constexpr int NF = NCOL / 16;
    constexpr int NK = K / 32;

    const int t = threadIdx.x;
    const int lane = t & 63;
    const int w = t >> 6;
    const int row0 = blockIdx.x * 64 + w * 16;

    const int arow = row0 + (lane & 15);
    const bool rowok = arow < nrows;
    const float* xrow = X + (size_t)arow * K + ((lane >> 4) * 8);

    f32x4 acc[NF];
#pragma unroll
    for (int c = 0; c < NF; ++c) acc[c] = (f32x4){0.f, 0.f, 0.f, 0.f};

#pragma unroll 2
    for (int kk = 0; kk < NK; ++kk) {
        float4 v0 = make_float4(0.f, 0.f, 0.f, 0.f);
        float4 v1 = v0;
        if (rowok) {
            v0 = *(const float4*)&xrow[kk * 32];
            v1 = *(const float4*)&xrow[kk * 32 + 4];
        }
        float a[8] = {v0.x, v0.y, v0.z, v0.w, v1.x, v1.y, v1.z, v1.w};
        short8v ah, al;
#pragma unroll
        for (int j = 0; j < 8; ++j) {
            unsigned short hb = f2bf_rne(a[j]);
            ah[j] = (short)hb;
            al[j] = (short)f2bf_rne(a[j] - bf2f(hb));
        }
        const unsigned short* wfk = wf + (size_t)(kk * NF * 2) * 512 + lane * 8;
        short8v bh[NF], bl[NF];
#pragma unroll
        for (int c = 0; c < NF; ++c) {
            bh[c] = *(const short8v*)(wfk + (c * 2 + 0) * 512);
            bl[c] = *(const short8v*)(wfk + (c * 2 + 1) * 512);
        }
#pragma unroll
        for (int c = 0; c < NF; ++c) {
            acc[c] = __builtin_amdgcn_mfma_f32_16x16x32_bf16(ah, bh[c], acc[c], 0, 0, 0);
            acc[c] = __builtin_amdgcn_mfma_f32_16x16x32_bf16(al, bh[c], acc[c], 0, 0, 0);
            acc[c] = __builtin_amdgcn_mfma_f32_16x16x32_bf16(ah, bl[c], acc[c], 0, 0, 0);
        }
    }

#pragma unroll
    for (int c = 0; c < NF; ++c) {
        int gcol = c * 16 + (lane & 15);
#pragma unroll
        for (int q = 0; q < 4; ++q) {
            int grow = row0 + (lane >> 4) * 4 + q;
            if (grow < nrows) Y[(size_t)grow * NCOL + gcol] = (_Float16)acc[c][q];
        }
    }
}

// ---------------------------------------------------------------------------
// Gather phase helper (device): wave w gathers its 16 node-rows (2 nodes x
// 32 lanes per pass) from fp16 hsrc into gtile[16][136] fp16.
// ---------------------------------------------------------------------------
template <bool ELU>
__device__ inline void gather_to_lds(const _Float16* __restrict__ hsrc,
                                     const int* __restrict__ row_ptr,
                                     const int* __restrict__ csr,
                                     const float* __restrict__ dis,
                                     _Float16 (*gtile)[136],
                                     int row0, int lane, int n) {
    const half4v* h4 = (const half4v*)hsrc;
    const int l = lane & 31;
    for (int p = 0; p < 8; ++p) {
        int lr = p * 2 + (lane >> 5);
        int node = row0 + lr;
        float ax = 0.f, ay = 0.f, az = 0.f, aw = 0.f;
        if (node < n) {
            int beg = (node == 0) ? 0 : row_ptr[node - 1];
            int end = row_ptr[node];
            float dd = dis[node];
            half4v self = h4[(size_t)node * 32 + l];
            ax = (float)self[0] * dd; ay = (float)self[1] * dd;
            az = (float)self[2] * dd; aw = (float)self[3] * dd;
            int j = beg;
            for (; j + 4 <= end; j += 4) {
                int s0 = csr[j + 0], s1 = csr[j + 1], s2 = csr[j + 2], s3 = csr[j + 3];
                float d0 = dis[s0], d1 = dis[s1], d2 = dis[s2], d3 = dis[s3];
                half4v v0 = h4[(size_t)s0 * 32 + l];
                half4v v1 = h4[(size_t)s1 * 32 + l];
                half4v v2 = h4[(size_t)s2 * 32 + l];
                half4v v3 = h4[(size_t)s3 * 32 + l];
                ax += (float)v0[0] * d0 + (float)v1[0] * d1 + (float)v2[0] * d2 + (float)v3[0] * d3;
                ay += (float)v0[1] * d0 + (float)v1[1] * d1 + (float)v2[1] * d2 + (float)v3[1] * d3;
                az += (float)v0[2] * d0 + (float)v1[2] * d1 + (float)v2[2] * d2 + (float)v3[2] * d3;
                aw += (float)v0[3] * d0 + (float)v1[3] * d1 + (float)v2[3] * d2 + (float)v3[3] * d3;
            }
            for (; j < end; ++j) {
                int s = csr[j];
                float ds = dis[s];
                half4v v = h4[(size_t)s * 32 + l];
                ax += (float)v[0] * ds; ay += (float)v[1] * ds;
                az += (float)v[2] * ds; aw += (float)v[3] * ds;
            }
            ax *= dd; ay *= dd; az *= dd; aw *= dd;
            if (ELU) {
                ax = (ax > 0.f) ? ax : expm1f(ax);
                ay = (ay > 0.f) ? ay : expm1f(ay);
                az = (az > 0.f) ? az : expm1f(az);
                aw = (aw > 0.f) ? aw : expm1f(aw);
            }
        }
        half4v o;
        o[0] = (_Float16)ax; o[1] = (_Float16)ay; o[2] = (_Float16)az; o[3] = (_Float16)aw;
        *(half4v*)&gtile[lr][l * 4] = o;
    }
}

// ---------------------------------------------------------------------------
// Fused layer-2: C16 = gather(A16) -> elu -> @W2 (3-term compensated MFMA).
// ---------------------------------------------------------------------------
__global__ __launch_bounds__(256, 6) void fused_gather_gemm_kernel(
    const _Float16* __restrict__ hsrc, const int* __restrict__ row_ptr,
    const int* __restrict__ csr, const float* __restrict__ dis,
    const unsigned short* __restrict__ wf, _Float16* __restrict__ Y, int n)
{
    __shared__ _Float16 gtile[4][16][136];
    const int t = threadIdx.x;
    const int lane = t & 63;
    const int w = t >> 6;
    const int row0 = blockIdx.x * 64 + w * 16;

    gather_to_lds<true>(hsrc, row_ptr, csr, dis, gtile[w], row0, lane, n);
    __syncthreads();

    f32x4 acc[8];
#pragma unroll
    for (int c = 0; c < 8; ++c) acc[c] = (f32x4){0.f, 0.f, 0.f, 0.f};

#pragma unroll
    for (int kk = 0; kk < 4; ++kk) {   // K=128
        half8v av = *(const half8v*)&gtile[w][lane & 15][kk * 32 + (lane >> 4) * 8];
        short8v ah, al;
#pragma unroll
        for (int j = 0; j < 8; ++j) {
            float f = (float)av[j];
            unsigned short hb = f2bf_rne(f);
            ah[j] = (short)hb;
            al[j] = (short)f2bf_rne(f - bf2f(hb));   // exact (fp16 -> bf16 hi/lo)
        }
        const unsigned short* wfk = wf + (size_t)(kk * 16) * 512 + lane * 8;
#pragma unroll
        for (int c = 0; c < 8; ++c) {
            short8v bh = *(const short8v*)(wfk + (c * 2 + 0) * 512);
            short8v bl = *(const short8v*)(wfk + (c * 2 + 1) * 512);
            acc[c] = __builtin_amdgcn_mfma_f32_16x16x32_bf16(ah, bh, acc[c], 0, 0, 0);
            acc[c] = __builtin_amdgcn_mfma_f32_16x16x32_bf16(al, bh, acc[c], 0, 0, 0);
            acc[c] = __builtin_amdgcn_mfma_f32_16x16x32_bf16(ah, bl, acc[c], 0, 0, 0);
        }
    }

#pragma unroll
    for (int c = 0; c < 8; ++c) {
        int gcol = c * 16 + (lane & 15);
#pragma unroll
        for (int q = 0; q < 4; ++q) {
            int grow = row0 + (lane >> 4) * 4 + q;
            if (grow < n) Y[(size_t)grow * 128 + gcol] = (_Float16)acc[c][q];
        }
    }
}

// ---------------------------------------------------------------------------
// Fused heads: Z16 = lrelu(lrelu(gather(C16)@H1 + b1)@H2 + b2).
// t1 overlays gtile (stage-1 fully consumes it before the overwrite).
// ---------------------------------------------------------------------------
__global__ __launch_bounds__(256, 6) void fused_gather_heads_kernel(
    const _Float16* __restrict__ hsrc, const int* __restrict__ row_ptr,
    const int* __restrict__ csr, const float* __restrict__ dis,
    const unsigned short* __restrict__ h1f, const unsigned short* __restrict__ h2f,
    const float* __restrict__ bcat1, const float* __restrict__ bcat2,
    _Float16* __restrict__ Z, int n)
{
    __shared__ _Float16 gtile[4][16][136];
    const int t = threadIdx.x;
    const int lane = t & 63;
    const int w = t >> 6;
    const int row0 = blockIdx.x * 64 + w * 16;

    gather_to_lds<false>(hsrc, row_ptr, csr, dis, gtile[w], row0, lane, n);
    __syncthreads();

    // stage 1: acc = embed @ H1
    f32x4 acc[8];
#pragma unroll
    for (int c = 0; c < 8; ++c) acc[c] = (f32x4){0.f, 0.f, 0.f, 0.f};

#pragma unroll
    for (int kk = 0; kk < 4; ++kk) {
        half8v av = *(const half8v*)&gtile[w][lane & 15][kk * 32 + (lane >> 4) * 8];
        short8v ah, al;
#pragma unroll
        for (int j = 0; j < 8; ++j) {
            float f = (float)av[j];
            unsigned short hb = f2bf_rne(f);
            ah[j] = (short)hb;
            al[j] = (short)f2bf_rne(f - bf2f(hb));
        }
        const unsigned short* wfk = h1f + (size_t)(kk * 16) * 512 + lane * 8;
#pragma unroll
        for (int c = 0; c < 8; ++c) {
            short8v bh = *(const short8v*)(wfk + (c * 2 + 0) * 512);
            short8v bl = *(const short8v*)(wfk + (c * 2 + 1) * 512);
            acc[c] = __builtin_amdgcn_mfma_f32_16x16x32_bf16(ah, bh, acc[c], 0, 0, 0);
            acc[c] = __builtin_amdgcn_mfma_f32_16x16x32_bf16(al, bh, acc[c], 0, 0, 0);
            acc[c] = __builtin_amdgcn_mfma_f32_16x16x32_bf16(ah, bl, acc[c], 0, 0, 0);
        }
    }
    __syncthreads();   // all stage-1 gtile reads complete before overlay

    // t1 = lrelu(acc + b1) -> fp16 -> gtile overlay (C/D layout scatter)
#pragma unroll
    for (int c = 0; c < 8; ++c) {
        int col = c * 16 + (lane & 15);
        float bv = bcat1[col];
#pragma unroll
        for (int q = 0; q < 4; ++q) {
            int r = (lane >> 4) * 4 + q;
            float o = acc[c][q] + bv;
            o = (o > 0.f) ? o : 0.01f * o;
            gtile[w][r][col] = (_Float16)o;
        }
    }
    __syncthreads();

    // stage 2: acc2 = t1 @ H2 (block-diag)
    f32x4 acc2[4];
#pragma unroll
    for (int c = 0; c < 4; ++c) acc2[c] = (f32x4){0.f, 0.f, 0.f, 0.f};

#pragma unroll
    for (int kk = 0; kk < 4; ++kk) {
        half8v av = *(const half8v*)&gtile[w][lane & 15][kk * 32 + (lane >> 4) * 8];
        short8v ah, al;
#pragma unroll
        for (int j = 0; j < 8; ++j) {
            float f = (float)av[j];
            unsigned short hb = f2bf_rne(f);
            ah[j] = (short)hb;
            al[j] = (short)f2bf_rne(f - bf2f(hb));
        }
        const unsigned short* wfk = h2f + (size_t)(kk * 8) * 512 + lane * 8;
#pragma unroll
        for (int c = 0; c < 4; ++c) {
            short8v bh = *(const short8v*)(wfk + (c * 2 + 0) * 512);
            short8v bl = *(const short8v*)(wfk + (c * 2 + 1) * 512);
            acc2[c] = __builtin_amdgcn_mfma_f32_16x16x32_bf16(ah, bh, acc2[c], 0, 0, 0);
            acc2[c] = __builtin_amdgcn_mfma_f32_16x16x32_bf16(al, bh, acc2[c], 0, 0, 0);
            acc2[c] = __builtin_amdgcn_mfma_f32_16x16x32_bf16(ah, bl, acc2[c], 0, 0, 0);
        }
    }

#pragma unroll
    for (int c = 0; c < 4; ++c) {
        int gcol = c * 16 + (lane & 15);
        float bv = bcat2[gcol];
#pragma unroll
        for (int q = 0; q < 4; ++q) {
            int grow = row0 + (lane >> 4) * 4 + q;
            if (grow < n) {
                float o = acc2[c][q] + bv;
                o = (o > 0.f) ? o : 0.01f * o;
                Z[(size_t)grow * 64 + gcol] = (_Float16)o;
            }
        }
    }
}

// ---------------------------------------------------------------------------
// decoder: Z fp16, layout [node][64] = [tf2(32) | tg2(32)]; 8 lanes/sample.
// ---------------------------------------------------------------------------
__global__ void dot_kernel(const _Float16* __restrict__ Z,
                           const int* __restrict__ ts, float* __restrict__ out, int m) {
    int gid = blockIdx.x * 256 + threadIdx.x;
    int s = gid >> 3;
    int l = gid & 7;
    if (s >= m) return;
    int ti = ts[2 * s + 0];
    int ui = ts[2 * s + 1];
    const half4v* Z4 = (const half4v*)Z;
    half4v a = Z4[(size_t)ti * 16 + l];
    half4v b = Z4[(size_t)ui * 16 + 8 + l];
    float d = (float)a[0] * (float)b[0] + (float)a[1] * (float)b[1]
            + (float)a[2] * (float)b[2] + (float)a[3] * (float)b[3];
    d += __shfl_down(d, 4, 8);
    d += __shfl_down(d, 2, 8);
    d += __shfl_down(d, 1, 8);
    if (l == 0) out[s] = d;
}

// ---------------------------------------------------------------------------
extern "C" void kernel_launch(void* const* d_in, const int* in_sizes, int n_in,
                              void* d_out, int out_size, void* d_ws, size_t ws_size,
                              hipStream_t stream) {
    const float* x     = (const float*)d_in[0];
    const int*   ei    = (const int*)d_in[1];
    const int*   ts    = (const int*)d_in[2];
    const float* W1    = (const float*)d_in[3];
    const float* W2    = (const float*)d_in[4];
    const float* tf_w1 = (const float*)d_in[5];
    const float* tf_b1 = (const float*)d_in[6];
    const float* tf_w2 = (const float*)d_in[7];
    const float* tf_b2 = (const float*)d_in[8];
    const float* tg_w1 = (const float*)d_in[9];
    const float* tg_b1 = (const float*)d_in[10];
    const float* tg_w2 = (const float*)d_in[11];
    const float* tg_b2 = (const float*)d_in[12];
    float* out = (float*)d_out;

    const int n = in_sizes[0] / 256;   // 50000
    const int e = in_sizes[1] / 2;     // 640000
    const int m = in_sizes[2] / 2;     // 400000
    const int* src = ei;
    const int* dstp = ei + e;

    // workspace layout (float units):
    //   dis[50176] | row_ptr[50176] (partials at +50048) | ideg/csr[640064] |
    //   wfrag[73728] (147456 shorts) | bcat1[128] bcat2[64] | A | B | C
    // A16 in A region, Z16 in B region, C16 in C region (all fp16 in fp32-sized slots).
    float* wsf = (float*)d_ws;
    float* dis     = wsf;
    int*   row_ptr = (int*)(wsf + 50176);
    int*   partials = row_ptr + 50048;
    int*   ideg    = (int*)(wsf + 100352);
    int*   csr     = (int*)(wsf + 100352);
    unsigned short* wfrag = (unsigned short*)(wsf + 740416);
    unsigned short* w1f = wfrag;
    unsigned short* w2f = wfrag + 65536;
    unsigned short* h1f = wfrag + 98304;
    unsigned short* h2f = wfrag + 131072;
    float* bcat1 = wsf + 740416 + 73728;
    float* bcat2 = wsf + 814272;
    float* A = wsf + 814336;
    float* B = A + (size_t)n * 128;
    float* C = B + (size_t)n * 128;
    _Float16* A16 = (_Float16*)A;
    _Float16* C16 = (_Float16*)C;
    _Float16* Z16 = (_Float16*)B;   // heads output in B region (C16 is read source)

    const int nb_n = (n + 255) / 256;
    const int nb_e = (e + 255) / 256;
    const int nsb  = (n + 1023) / 1024;  // 49
    const int gm   = (n + 63) / 64;      // 782

    // 1) CSR build + normalization (parallel scan)
    zero_ideg_kernel<<<nb_n, 256, 0, stream>>>(ideg, n);
    ideg_accum_kernel<<<nb_e, 256, 0, stream>>>(ideg, dstp, e);
    scan_blk_kernel<<<nsb, 256, 0, stream>>>(ideg, row_ptr, dis, partials, n);
    scan_part_kernel<<<1, 64, 0, stream>>>(partials, nsb);
    scan_add_kernel<<<nb_n, 256, 0, stream>>>(row_ptr, partials, n);
    fill_kernel<<<nb_e, 256, 0, stream>>>(src, dstp, row_ptr, csr, e);

    // 1b) weight prep (fragment order) + biases
    prep_weights_kernel<<<(147648 + 255) / 256, 256, 0, stream>>>(
        W1, W2, tf_w1, tf_b1, tf_w2, tf_b2, tg_w1, tg_b1, tg_w2, tg_b2,
        wfrag, bcat1, bcat2);

    // 2) layer 1: A16 = x@W1
    mfma_gemm_kernel<256, 128><<<gm, 256, 0, stream>>>(x, w1f, A16, n);

    // 3) fused layer 2: C16 = elu(gather(A16)) @ W2
    fused_gather_gemm_kernel<<<gm, 256, 0, stream>>>(A16, row_ptr, csr, dis, w2f, C16, n);

    // 4) fused heads: Z16 = heads(gather(C16))
    fused_gather_heads_kernel<<<gm, 256, 0, stream>>>(
        C16, row_ptr, csr, dis, h1f, h2f, bcat1, bcat2, Z16, n);

    // 5) decoder
    dot_kernel<<<(m * 8 + 255) / 256, 256, 0, stream>>>(Z16, ts, out, m);
}

// Round 13
// 302.028 us; speedup vs baseline: 1.0667x; 1.0667x over previous
//
#include <hip/hip_runtime.h>
#include <hip/hip_bf16.h>
#include <math.h>

// Problem constants: N=50000, E=640000, M=400000
// D_IN=256, H1=128, H2=128, H3=64, D_OUT=32
//
// Round 13: revert round-12 fusion (gather TLP was grid-starved: 60us fused
// vs 37us split). Back to round-11 split structure, plus:
//   - gather: 16 lanes/node, half8v 16B loads (2x chains/block, grid 3125)
//   - dot: 4 lanes/sample, half8v (2x samples/wave)

typedef __attribute__((ext_vector_type(8))) short short8v;     // 8 bf16 (4 VGPR)
typedef __attribute__((ext_vector_type(4))) float f32x4;       // MFMA acc
typedef __attribute__((ext_vector_type(4))) _Float16 half4v;   // 8B fp16 vector
typedef __attribute__((ext_vector_type(8))) _Float16 half8v;   // 16B fp16 vector

__device__ inline unsigned short f2bf_rne(float f) {
    unsigned u = __float_as_uint(f);
    unsigned r = u + 0x7FFFu + ((u >> 16) & 1u);
    return (unsigned short)(r >> 16);
}
__device__ inline float bf2f(unsigned short h) {
    return __uint_as_float(((unsigned)h) << 16);
}

// ---------------------------------------------------------------------------
// CSR build + norm
// ---------------------------------------------------------------------------
__global__ void zero_ideg_kernel(int* __restrict__ ideg, int n) {
    int i = blockIdx.x * 256 + threadIdx.x;
    if (i < n) ideg[i] = 0;
}

__global__ void ideg_accum_kernel(int* __restrict__ ideg, const int* __restrict__ dst, int e) {
    int i = blockIdx.x * 256 + threadIdx.x;
    if (i < e) atomicAdd(&ideg[dst[i]], 1);
}

__global__ __launch_bounds__(256) void scan_blk_kernel(const int* __restrict__ ideg,
                                                       int* __restrict__ row_ptr,
                                                       float* __restrict__ dis,
                                                       int* __restrict__ partials, int n) {
    __shared__ int wsum[4];
    const int t = threadIdx.x;
    const int lane = t & 63;
    const int wid = t >> 6;
    const int i0 = blockIdx.x * 1024 + t * 4;
    int4 v = make_int4(0, 0, 0, 0);
    if (i0 + 3 < n) {
        v = *(const int4*)&ideg[i0];
    } else if (i0 < n) {
        v.x = ideg[i0];
        if (i0 + 1 < n) v.y = ideg[i0 + 1];
        if (i0 + 2 < n) v.z = ideg[i0 + 2];
    }
    if (i0 < n) {
        dis[i0] = rsqrtf(1.f + (float)v.x);
        if (i0 + 1 < n) dis[i0 + 1] = rsqrtf(1.f + (float)v.y);
        if (i0 + 2 < n) dis[i0 + 2] = rsqrtf(1.f + (float)v.z);
        if (i0 + 3 < n) dis[i0 + 3] = rsqrtf(1.f + (float)v.w);
    }
    int s = v.x + v.y + v.z + v.w;
    int incl = s;
#pragma unroll
    for (int off = 1; off < 64; off <<= 1) {
        int tv = __shfl_up(incl, off, 64);
        if (lane >= off) incl += tv;
    }
    if (lane == 63) wsum[wid] = incl;
    __syncthreads();
    if (t == 0) {
        int a = 0;
#pragma unroll
        for (int ww = 0; ww < 4; ++ww) { int tmp = wsum[ww]; wsum[ww] = a; a += tmp; }
    }
    __syncthreads();
    int ex = wsum[wid] + incl - s;
    if (i0 < n) {
        row_ptr[i0] = ex;
        if (i0 + 1 < n) row_ptr[i0 + 1] = ex + v.x;
        if (i0 + 2 < n) row_ptr[i0 + 2] = ex + v.x + v.y;
        if (i0 + 3 < n) row_ptr[i0 + 3] = ex + v.x + v.y + v.z;
    }
    if (t == 255) partials[blockIdx.x] = wsum[3] + incl;
}

__global__ void scan_part_kernel(int* __restrict__ partials, int nb) {
    int lane = threadIdx.x;
    int v = (lane < nb) ? partials[lane] : 0;
    int incl = v;
#pragma unroll
    for (int off = 1; off < 64; off <<= 1) {
        int tv = __shfl_up(incl, off, 64);
        if (lane >= off) incl += tv;
    }
    if (lane < nb) partials[lane] = incl - v;
}

__global__ void scan_add_kernel(int* __restrict__ row_ptr, const int* __restrict__ partials, int n) {
    int i = blockIdx.x * 256 + threadIdx.x;
    if (i < n) row_ptr[i] += partials[i >> 10];
}

__global__ void fill_kernel(const int* __restrict__ src, const int* __restrict__ dst,
                            int* __restrict__ row_ptr, int* __restrict__ csr, int e) {
    int i = blockIdx.x * 256 + threadIdx.x;
    if (i < e) {
        int d = dst[i];
        int pos = atomicAdd(&row_ptr[d], 1);
        csr[pos] = src[i];
    }
}

// ---------------------------------------------------------------------------
// Weight prep in MFMA-fragment order.
// ---------------------------------------------------------------------------
__global__ void prep_weights_kernel(
    const float* __restrict__ W1, const float* __restrict__ W2,
    const float* __restrict__ tfw1, const float* __restrict__ tfb1,
    const float* __restrict__ tfw2, const float* __restrict__ tfb2,
    const float* __restrict__ tgw1, const float* __restrict__ tgb1,
    const float* __restrict__ tgw2, const float* __restrict__ tgb2,
    unsigned short* __restrict__ wf,
    float* __restrict__ bcat1, float* __restrict__ bcat2)
{
    int id = blockIdx.x * 256 + threadIdx.x;
    if (id >= 147456) {
        if (id < 147456 + 128) {
            int c = id - 147456;
            bcat1[c] = (c < 64) ? tfb1[c] : tgb1[c - 64];
        } else if (id < 147456 + 192) {
            int c = id - 147456 - 128;
            bcat2[c] = (c < 32) ? tfb2[c] : tgb2[c - 32];
        }
        return;
    }
    int base, NF;
    int lid;
    if (id < 65536)       { base = 0;      NF = 8; lid = id; }
    else if (id < 98304)  { base = 65536;  NF = 8; lid = id - 65536; }
    else if (id < 131072) { base = 98304;  NF = 8; lid = id - 98304; }
    else                  { base = 131072; NF = 4; lid = id - 131072; }

    int j    = lid & 7;
    int lane = (lid >> 3) & 63;
    int h    = (lid >> 9) & 1;
    int rest = lid >> 10;
    int c    = rest % NF;
    int kk   = rest / NF;
    int k    = kk * 32 + (lane >> 4) * 8 + j;
    int col  = c * 16 + (lane & 15);

    float w;
    if (id < 65536) {                 // W1: [256][128]
        w = W1[k * 128 + col];
    } else if (id < 98304) {          // W2: [128][128]
        w = W2[k * 128 + col];
    } else if (id < 131072) {         // H1 cat: [128][128] = [tf_w1 | tg_w1]
        w = (col < 64) ? tfw1[k * 64 + col] : tgw1[k * 64 + (col - 64)];
    } else {                          // H2 block-diag: [128][64]
        w = 0.f;
        if (k < 64 && col < 32) w = tfw2[k * 32 + col];
        else if (k >= 64 && col >= 32) w = tgw2[(k - 64) * 32 + (col - 32)];
    }
    unsigned short hb = f2bf_rne(w);
    wf[base + lid] = h ? f2bf_rne(w - bf2f(hb)) : hb;
}

// ---------------------------------------------------------------------------
// LDS-free MFMA GEMM. OUT_HALF: write _Float16 (for gather-consumed outputs).
// ---------------------------------------------------------------------------
template <int K, int NCOL, bool ELU_IN, bool LRELU, bool BIAS, bool OUT_HALF>
__global__ __launch_bounds__(256) void mfma_gemm_kernel(
    const float* __restrict__ X, const unsigned short* __restrict__ wf,
    const float* __restrict__ bias, void* __restrict__ Yv, int nrows)
{
    constexpr int NF = NCOL / 16;
    constexpr int NK = K / 32;

    const int t = threadIdx.x;
    const int lane = t & 63;
    const int w = t >> 6;
    const int row0 = blockIdx.x * 64 + w * 16;

    const int arow = row0 + (lane & 15);
    const bool rowok = arow < nrows;
    const float* xrow = X + (size_t)arow * K + ((lane >> 4) * 8);

    f32x4 acc[NF];
#pragma unroll
    for (int c = 0; c < NF; ++c) acc[c] = (f32x4){0.f, 0.f, 0.f, 0.f};

#pragma unroll 2
    for (int kk = 0; kk < NK; ++kk) {
        float4 v0 = make_float4(0.f, 0.f, 0.f, 0.f);
        float4 v1 = v0;
        if (rowok) {
            v0 = *(const float4*)&xrow[kk * 32];
            v1 = *(const float4*)&xrow[kk * 32 + 4];
        }
        if (ELU_IN) {
            v0.x = (v0.x > 0.f) ? v0.x : expm1f(v0.x);
            v0.y = (v0.y > 0.f) ? v0.y : expm1f(v0.y);
            v0.z = (v0.z > 0.f) ? v0.z : expm1f(v0.z);
            v0.w = (v0.w > 0.f) ? v0.w : expm1f(v0.w);
            v1.x = (v1.x > 0.f) ? v1.x : expm1f(v1.x);
            v1.y = (v1.y > 0.f) ? v1.y : expm1f(v1.y);
            v1.z = (v1.z > 0.f) ? v1.z : expm1f(v1.z);
            v1.w = (v1.w > 0.f) ? v1.w : expm1f(v1.w);
        }
        float a[8] = {v0.x, v0.y, v0.z, v0.w, v1.x, v1.y, v1.z, v1.w};
        short8v ah, al;
#pragma unroll
        for (int j = 0; j < 8; ++j) {
            unsigned short hb = f2bf_rne(a[j]);
            ah[j] = (short)hb;
            al[j] = (short)f2bf_rne(a[j] - bf2f(hb));
        }
        const unsigned short* wfk = wf + (size_t)(kk * NF * 2) * 512 + lane * 8;
        short8v bh[NF], bl[NF];
#pragma unroll
        for (int c = 0; c < NF; ++c) {
            bh[c] = *(const short8v*)(wfk + (c * 2 + 0) * 512);
            bl[c] = *(const short8v*)(wfk + (c * 2 + 1) * 512);
        }
#pragma unroll
        for (int c = 0; c < NF; ++c) {
            acc[c] = __builtin_amdgcn_mfma_f32_16x16x32_bf16(ah, bh[c], acc[c], 0, 0, 0);
            acc[c] = __builtin_amdgcn_mfma_f32_16x16x32_bf16(al, bh[c], acc[c], 0, 0, 0);
            acc[c] = __builtin_amdgcn_mfma_f32_16x16x32_bf16(ah, bl[c], acc[c], 0, 0, 0);
        }
    }

#pragma unroll
    for (int c = 0; c < NF; ++c) {
        int gcol = c * 16 + (lane & 15);
        float bv = BIAS ? bias[gcol] : 0.f;
#pragma unroll
        for (int q = 0; q < 4; ++q) {
            int grow = row0 + (lane >> 4) * 4 + q;
            if (grow < nrows) {
                float o = acc[c][q] + bv;
                if (LRELU) o = (o > 0.f) ? o : 0.01f * o;
                if (OUT_HALF) ((_Float16*)Yv)[(size_t)grow * NCOL + gcol] = (_Float16)o;
                else          ((float*)Yv)[(size_t)grow * NCOL + gcol] = o;
            }
        }
    }
}

// ---------------------------------------------------------------------------
// Fused heads (round-11 form): Z = lrelu(lrelu(X@H1+b1)@H2+b2), Z in fp16.
// ---------------------------------------------------------------------------
__global__ __launch_bounds__(256) void fused_heads_kernel(
    const float* __restrict__ X, const unsigned short* __restrict__ h1f,
    const unsigned short* __restrict__ h2f, const float* __restrict__ bcat1,
    const float* __restrict__ bcat2, _Float16* __restrict__ Z, int nrows)
{
    constexpr int LDT = 136;
    __shared__ unsigned short t1h[4][16][LDT];
    __shared__ unsigned short t1l[4][16][LDT];

    const int t = threadIdx.x;
    const int lane = t & 63;
    const int w = t >> 6;
    const int row0 = blockIdx.x * 64 + w * 16;

    const int arow = row0 + (lane & 15);
    const bool rowok = arow < nrows;
    const float* xrow = X + (size_t)arow * 128 + ((lane >> 4) * 8);

    f32x4 acc[8];
#pragma unroll
    for (int c = 0; c < 8; ++c) acc[c] = (f32x4){0.f, 0.f, 0.f, 0.f};

#pragma unroll 2
    for (int kk = 0; kk < 4; ++kk) {
        float4 v0 = make_float4(0.f, 0.f, 0.f, 0.f);
        float4 v1 = v0;
        if (rowok) {
            v0 = *(const float4*)&xrow[kk * 32];
            v1 = *(const float4*)&xrow[kk * 32 + 4];
        }
        float a[8] = {v0.x, v0.y, v0.z, v0.w, v1.x, v1.y, v1.z, v1.w};
        short8v ah, al;
#pragma unroll
        for (int j = 0; j < 8; ++j) {
            unsigned short hb = f2bf_rne(a[j]);
            ah[j] = (short)hb;
            al[j] = (short)f2bf_rne(a[j] - bf2f(hb));
        }
        const unsigned short* wfk = h1f + (size_t)(kk * 16) * 512 + lane * 8;
        short8v bh[8], bl[8];
#pragma unroll
        for (int c = 0; c < 8; ++c) {
            bh[c] = *(const short8v*)(wfk + (c * 2 + 0) * 512);
            bl[c] = *(const short8v*)(wfk + (c * 2 + 1) * 512);
        }
#pragma unroll
        for (int c = 0; c < 8; ++c) {
            acc[c] = __builtin_amdgcn_mfma_f32_16x16x32_bf16(ah, bh[c], acc[c], 0, 0, 0);
            acc[c] = __builtin_amdgcn_mfma_f32_16x16x32_bf16(al, bh[c], acc[c], 0, 0, 0);
            acc[c] = __builtin_amdgcn_mfma_f32_16x16x32_bf16(ah, bl[c], acc[c], 0, 0, 0);
        }
    }

#pragma unroll
    for (int c = 0; c < 8; ++c) {
        int col = c * 16 + (lane & 15);
        float bv = bcat1[col];
#pragma unroll
        for (int q = 0; q < 4; ++q) {
            int r = (lane >> 4) * 4 + q;
            float o = acc[c][q] + bv;
            o = (o > 0.f) ? o : 0.01f * o;
            unsigned short hb = f2bf_rne(o);
            t1h[w][r][col] = hb;
            t1l[w][r][col] = f2bf_rne(o - bf2f(hb));
        }
    }

    f32x4 acc2[4];
#pragma unroll
    for (int c = 0; c < 4; ++c) acc2[c] = (f32x4){0.f, 0.f, 0.f, 0.f};

#pragma unroll
    for (int kk = 0; kk < 4; ++kk) {
        int koff = kk * 32 + (lane >> 4) * 8;
        short8v ah = *(const short8v*)&t1h[w][lane & 15][koff];
        short8v al = *(const short8v*)&t1l[w][lane & 15][koff];
        const unsigned short* wfk = h2f + (size_t)(kk * 8) * 512 + lane * 8;
#pragma unroll
        for (int c = 0; c < 4; ++c) {
            short8v bh = *(const short8v*)(wfk + (c * 2 + 0) * 512);
            short8v bl = *(const short8v*)(wfk + (c * 2 + 1) * 512);
            acc2[c] = __builtin_amdgcn_mfma_f32_16x16x32_bf16(ah, bh, acc2[c], 0, 0, 0);
            acc2[c] = __builtin_amdgcn_mfma_f32_16x16x32_bf16(al, bh, acc2[c], 0, 0, 0);
            acc2[c] = __builtin_amdgcn_mfma_f32_16x16x32_bf16(ah, bl, acc2[c], 0, 0, 0);
        }
    }

#pragma unroll
    for (int c = 0; c < 4; ++c) {
        int gcol = c * 16 + (lane & 15);
        float bv = bcat2[gcol];
#pragma unroll
        for (int q = 0; q < 4; ++q) {
            int grow = row0 + (lane >> 4) * 4 + q;
            if (grow < nrows) {
                float o = acc2[c][q] + bv;
                o = (o > 0.f) ? o : 0.01f * o;
                Z[(size_t)grow * 64 + gcol] = (_Float16)o;
            }
        }
    }
}

// ---------------------------------------------------------------------------
// Gather: 16 lanes/node, half8v (16B) loads; fp32 accumulate/output.
// out[d,:] = dis[d]*(h[d]*dis[d] + sum h[s]*dis[s]); 16 nodes per 256-block.
// ---------------------------------------------------------------------------
__global__ __launch_bounds__(256) void gather_kernel(const _Float16* __restrict__ h,
                                                     const int* __restrict__ row_ptr,
                                                     const int* __restrict__ csr,
                                                     const float* __restrict__ dis,
                                                     float* __restrict__ outp, int n) {
    int node = blockIdx.x * 16 + (threadIdx.x >> 4);
    int l = threadIdx.x & 15;
    if (node >= n) return;
    int beg = (node == 0) ? 0 : row_ptr[node - 1];
    int end = row_ptr[node];
    float dd = dis[node];
    const half8v* h8 = (const half8v*)h;
    half8v self = h8[(size_t)node * 16 + l];
    float a[8];
#pragma unroll
    for (int q = 0; q < 8; ++q) a[q] = (float)self[q] * dd;
    int j = beg;
    for (; j + 4 <= end; j += 4) {
        int s0 = csr[j + 0], s1 = csr[j + 1], s2 = csr[j + 2], s3 = csr[j + 3];
        float d0 = dis[s0], d1 = dis[s1], d2 = dis[s2], d3 = dis[s3];
        half8v v0 = h8[(size_t)s0 * 16 + l];
        half8v v1 = h8[(size_t)s1 * 16 + l];
        half8v v2 = h8[(size_t)s2 * 16 + l];
        half8v v3 = h8[(size_t)s3 * 16 + l];
#pragma unroll
        for (int q = 0; q < 8; ++q)
            a[q] += (float)v0[q] * d0 + (float)v1[q] * d1 + (float)v2[q] * d2 + (float)v3[q] * d3;
    }
    for (; j < end; ++j) {
        int s = csr[j];
        float ds = dis[s];
        half8v v = h8[(size_t)s * 16 + l];
#pragma unroll
        for (int q = 0; q < 8; ++q) a[q] += (float)v[q] * ds;
    }
    float4 o0 = make_float4(a[0] * dd, a[1] * dd, a[2] * dd, a[3] * dd);
    float4 o1 = make_float4(a[4] * dd, a[5] * dd, a[6] * dd, a[7] * dd);
    *(float4*)&outp[(size_t)node * 128 + l * 8]     = o0;
    *(float4*)&outp[(size_t)node * 128 + l * 8 + 4] = o1;
}

// ---------------------------------------------------------------------------
// decoder: 4 lanes/sample, half8v; Z fp16 [node][64] = [tf2(32) | tg2(32)].
// ---------------------------------------------------------------------------
__global__ void dot_kernel(const _Float16* __restrict__ Z,
                           const int* __restrict__ ts, float* __restrict__ out, int m) {
    int gid = blockIdx.x * 256 + threadIdx.x;
    int s = gid >> 2;
    int l = gid & 3;
    if (s >= m) return;
    int ti = ts[2 * s + 0];
    int ui = ts[2 * s + 1];
    const half8v* Z8 = (const half8v*)Z;
    half8v a = Z8[(size_t)ti * 8 + l];
    half8v b = Z8[(size_t)ui * 8 + 4 + l];
    float d = 0.f;
#pragma unroll
    for (int q = 0; q < 8; ++q) d += (float)a[q] * (float)b[q];
    d += __shfl_down(d, 2, 4);
    d += __shfl_down(d, 1, 4);
    if (l == 0) out[s] = d;
}

// ---------------------------------------------------------------------------
extern "C" void kernel_launch(void* const* d_in, const int* in_sizes, int n_in,
                              void* d_out, int out_size, void* d_ws, size_t ws_size,
                              hipStream_t stream) {
    const float* x     = (const float*)d_in[0];
    const int*   ei    = (const int*)d_in[1];
    const int*   ts    = (const int*)d_in[2];
    const float* W1    = (const float*)d_in[3];
    const float* W2    = (const float*)d_in[4];
    const float* tf_w1 = (const float*)d_in[5];
    const float* tf_b1 = (const float*)d_in[6];
    const float* tf_w2 = (const float*)d_in[7];
    const float* tf_b2 = (const float*)d_in[8];
    const float* tg_w1 = (const float*)d_in[9];
    const float* tg_b1 = (const float*)d_in[10];
    const float* tg_w2 = (const float*)d_in[11];
    const float* tg_b2 = (const float*)d_in[12];
    float* out = (float*)d_out;

    const int n = in_sizes[0] / 256;   // 50000
    const int e = in_sizes[1] / 2;     // 640000
    const int m = in_sizes[2] / 2;     // 400000
    const int* src = ei;
    const int* dstp = ei + e;

    // workspace layout (float units):
    //   dis[50176] | row_ptr[50176] (partials at +50048) | ideg/csr[640064] |
    //   wfrag[73728] (147456 shorts) | bcat1[128] bcat2[64] | A | B | C
    float* wsf = (float*)d_ws;
    float* dis     = wsf;
    int*   row_ptr = (int*)(wsf + 50176);
    int*   partials = row_ptr + 50048;
    int*   ideg    = (int*)(wsf + 100352);
    int*   csr     = (int*)(wsf + 100352);
    unsigned short* wfrag = (unsigned short*)(wsf + 740416);
    unsigned short* w1f = wfrag;
    unsigned short* w2f = wfrag + 65536;
    unsigned short* h1f = wfrag + 98304;
    unsigned short* h2f = wfrag + 131072;
    float* bcat1 = wsf + 740416 + 73728;
    float* bcat2 = wsf + 814272;
    float* A = wsf + 814336;
    float* B = A + (size_t)n * 128;
    float* C = B + (size_t)n * 128;
    _Float16* A16 = (_Float16*)A;
    _Float16* C16 = (_Float16*)C;
    _Float16* Z16 = (_Float16*)C;   // heads output overlays C region

    const int nb_n = (n + 255) / 256;
    const int nb_e = (e + 255) / 256;
    const int nsb  = (n + 1023) / 1024;  // 49
    const int gg   = (n + 15) / 16;      // gather grid: 3125
    const int gm   = (n + 63) / 64;      // MFMA grid: 782

    // 1) CSR build + normalization (parallel scan)
    zero_ideg_kernel<<<nb_n, 256, 0, stream>>>(ideg, n);
    ideg_accum_kernel<<<nb_e, 256, 0, stream>>>(ideg, dstp, e);
    scan_blk_kernel<<<nsb, 256, 0, stream>>>(ideg, row_ptr, dis, partials, n);
    scan_part_kernel<<<1, 64, 0, stream>>>(partials, nsb);
    scan_add_kernel<<<nb_n, 256, 0, stream>>>(row_ptr, partials, n);
    fill_kernel<<<nb_e, 256, 0, stream>>>(src, dstp, row_ptr, csr, e);

    // 1b) weight prep (fragment order) + biases
    prep_weights_kernel<<<(147648 + 255) / 256, 256, 0, stream>>>(
        W1, W2, tf_w1, tf_b1, tf_w2, tf_b2, tg_w1, tg_b1, tg_w2, tg_b2,
        wfrag, bcat1, bcat2);

    // 2) layer 1: A16 = x@W1 (fp16 out) ; B = gather(A16) (fp32)
    mfma_gemm_kernel<256, 128, false, false, false, true><<<gm, 256, 0, stream>>>(x, w1f, nullptr, A16, n);
    gather_kernel<<<gg, 256, 0, stream>>>(A16, row_ptr, csr, dis, B, n);

    // 3) layer 2: C16 = elu(B)@W2 (fp16 out) ; A = gather(C16) (fp32 embed)
    mfma_gemm_kernel<128, 128, true, false, false, true><<<gm, 256, 0, stream>>>(B, w2f, nullptr, C16, n);
    gather_kernel<<<gg, 256, 0, stream>>>(C16, row_ptr, csr, dis, A, n);

    // 4) fused heads: Z16 = lrelu(lrelu(A@H1+b1)@H2+b2), fp16 [node][tf2|tg2]
    fused_heads_kernel<<<gm, 256, 0, stream>>>(A, h1f, h2f, bcat1, bcat2, Z16, n);

    // 5) decoder (4 lanes/sample)
    dot_kernel<<<(m * 4 + 255) / 256, 256, 0, stream>>>(Z16, ts, out, m);
}